// Round 19
// baseline (1919.130 us; speedup 1.0000x reference)
//
#include <hip/hip_runtime.h>
#include <hip/hip_bf16.h>
#include <cstdint>

#define B 2048
#define NL 32
#define FEAT 512
#define HID 512
#define HW 64
#define OUTSZ 42
#define G3 1536
#define LDIH 554   // gru_w_ih row stride
#define MB 16      // batch rows per block
#define NBLK (B/MB)   // 128
#define LDX 584    // lds_x row stride
#define LDH 520    // o1s row stride
#define CHW 16384  // bf16 elements per 32KB chunk

typedef __bf16 bf16x8 __attribute__((ext_vector_type(8)));
typedef unsigned short u16x8 __attribute__((ext_vector_type(8)));
typedef float f32x4 __attribute__((ext_vector_type(4)));
typedef __hip_bfloat16 bf16_t;

#define MFMA(a,b,c) __builtin_amdgcn_mfma_f32_16x16x32_bf16(a,b,c,0,0,0)

// Pace the register weight stream: before consuming the buffer loaded 2 ticks
// ago, allow only the newest 4 loads (1 tick) outstanding.
#define WAITV4() asm volatile("s_waitcnt vmcnt(4)" ::: "memory")
// Phase boundary: publish this wave's LDS ops, RAW barrier (register weight
// loads stay in flight — __syncthreads would drain vmcnt to 0).
#define PHASE_SYNC() do {                                            \
    asm volatile("s_waitcnt lgkmcnt(0)" ::: "memory");               \
    __builtin_amdgcn_s_barrier();                                    \
  } while (0)

static __device__ __forceinline__ float sigmoidf_(float x){ return 1.f/(1.f+__expf(-x)); }
static __device__ __forceinline__ float bf_lo(uint32_t u){
  union { uint32_t i; float f; } c; c.i = u << 16; return c.f;
}
static __device__ __forceinline__ float bf_hi(uint32_t u){
  union { uint32_t i; float f; } c; c.i = u & 0xffff0000u; return c.f;
}

#define MFMA4(ACC, A, W) do {                  \
    ACC[0] = MFMA(A, W[0], ACC[0]);            \
    ACC[1] = MFMA(A, W[1], ACC[1]);            \
    ACC[2] = MFMA(A, W[2], ACC[2]);            \
    ACC[3] = MFMA(A, W[3], ACC[3]);            \
  } while (0)

#define LOADW(W, SRC) do {                     \
    const bf16_t* _s = (SRC);                  \
    W[0] = *(const bf16x8*)(_s);               \
    W[1] = *(const bf16x8*)(_s + 512);         \
    W[2] = *(const bf16x8*)(_s + 1024);        \
    W[3] = *(const bf16x8*)(_s + 1536);        \
  } while (0)

// ---------------- one-time weight prep into STAGING layouts (verified r13/r16) ----------
// sA[54][512][32]: chunk (k0,g) at c=k0*3+g; row rp; granule gq holds k-quarter
//   half = gq ^ ((rp>>1)&3). sB[16][512][32]: lin1 chunks. sC[2][64][256]: lin2
//   k-halves, granule s holds g = s^(j&7). w_ssn[512][64]; w_ih512b, bias_comb.
__global__ __launch_bounds__(256) void prep4_kernel(
    const float* __restrict__ w_ih, const float* __restrict__ w_hh,
    const float* __restrict__ lin1_w, const float* __restrict__ lin2_w,
    const float* __restrict__ b_ih, const float* __restrict__ b_hh,
    bf16_t* __restrict__ sA, bf16_t* __restrict__ sB, bf16_t* __restrict__ sC,
    bf16_t* __restrict__ w_ssn, bf16_t* __restrict__ w_ih512b,
    float* __restrict__ bias_comb){
  const int NA = 54*CHW, NB2 = 16*CHW, NC2 = 2*CHW, NS = 512*64, NI = G3*512;
  const int total = NA+NB2+NC2+NS+NI+G3;
  for (int idx = blockIdx.x*256 + threadIdx.x; idx < total; idx += gridDim.x*256){
    int i = idx;
    if (i < NA){
      int c = i/CHW, r2 = i%CHW, rp = r2>>5, kk = r2&31, gq = kk>>3, e = kk&7;
      int k0 = c/3, g = c%3;
      int half = gq ^ ((rp>>1)&3);
      int orow = g*512 + rp;
      int k = k0*32 + half*8 + e;
      float v = (k < 512) ? w_hh[orow*512 + k]
              : ((k < 512+OUTSZ && g < 2) ? w_ih[(size_t)orow*LDIH + k] : 0.f);
      sA[i] = __float2bfloat16(v);
    } else if ((i -= NA) < NB2){
      int c = i/CHW, r2 = i%CHW, rp = r2>>5, kk = r2&31, gq = kk>>3, e = kk&7;
      int half = gq ^ ((rp>>1)&3);
      sB[i] = __float2bfloat16(lin1_w[rp*512 + c*32 + half*8 + e]);
    } else if ((i -= NB2) < NC2){
      int n = i/CHW, r2 = i%CHW, j = r2>>8, kk = r2&255, s = kk>>3, e = kk&7;
      int g = s ^ (j & 7);
      int k = n*256 + g*8 + e;
      float v = (j < OUTSZ) ? lin2_w[j*512 + k] : 0.f;
      sC[i] = __float2bfloat16(v);
    } else if ((i -= NC2) < NS){
      int j = i>>6, k = i&63;
      float v = (k < OUTSZ) ? w_ih[(size_t)(1024+j)*LDIH + 512 + k] : 0.f;
      w_ssn[i] = __float2bfloat16(v);
    } else if ((i -= NS) < NI){
      int r = i>>9, c = i&511;
      w_ih512b[i] = __float2bfloat16(w_ih[(size_t)r*LDIH + c]);
    } else {
      int j = i - NI;
      bias_comb[j] = b_ih[j] + (j < 1024 ? b_hh[j] : 0.f);
    }
  }
}

// ---------------- attention precompute (step-invariant) ----------------
__global__ __launch_bounds__(256) void att_kernel(const float* __restrict__ feat,
                                                  const float* __restrict__ att_w,
                                                  bf16_t* __restrict__ att_feat){
  int b = blockIdx.x;
  const float* fb = feat + (size_t)b * FEAT * HW;
  __shared__ float part[4][64];
  __shared__ float attv[64];
  int t = threadIdx.x;
  int s = t & 63, q = t >> 6;
  float acc = 0.f;
  for (int c = q*128; c < q*128 + 128; ++c)
    acc = fmaf(fb[c*HW + s], att_w[c], acc);
  part[q][s] = acc;
  __syncthreads();
  if (t < 64){
    float v = part[0][t] + part[1][t] + part[2][t] + part[3][t];
    float m = v;
    for (int o = 32; o > 0; o >>= 1) m = fmaxf(m, __shfl_xor(m, o));
    float e = __expf(v - m);
    float ssum = e;
    for (int o = 32; o > 0; o >>= 1) ssum += __shfl_xor(ssum, o);
    attv[t] = e / ssum * 2.0f;   // * BETA
  }
  __syncthreads();
  for (int c = t; c < FEAT; c += 256){
    const float4* row = (const float4*)(fb + c*HW);
    float a2 = 0.f;
    #pragma unroll
    for (int k = 0; k < 16; ++k){
      float4 v4 = row[k];
      a2 = fmaf(v4.x, attv[k*4+0], a2);
      a2 = fmaf(v4.y, attv[k*4+1], a2);
      a2 = fmaf(v4.z, attv[k*4+2], a2);
      a2 = fmaf(v4.w, attv[k*4+3], a2);
    }
    att_feat[(size_t)b*FEAT + c] = __float2bfloat16(a2);
  }
}

// ---------------- bf16 MFMA GEMM (NT), bf16 output (gi16 preamble) ----------------
__global__ __launch_bounds__(256) void gemm_mfma_bf(const bf16_t* __restrict__ A,
                                                    const bf16_t* __restrict__ W,
                                                    const float* __restrict__ bias,
                                                    bf16_t* __restrict__ C,
                                                    int K, int lda, int ldw, int ldc){
  const int tid = threadIdx.x;
  const int w = tid >> 6, lane = tid & 63;
  const int r = lane & 15, half = lane >> 4;
  const int m_base = blockIdx.y * 64;
  const int n_base = blockIdx.x * 64 + w * 16;
  const bf16_t* Ap = A + (size_t)(m_base + r)*lda + half*8;
  const bf16_t* Wp = W + (size_t)(n_base + r)*ldw + half*8;
  f32x4 acc[4] = {};
  for (int k0 = 0; k0 < K; k0 += 32){
    bf16x8 bfrag = *(const bf16x8*)(Wp + k0);
    #pragma unroll
    for (int i = 0; i < 4; ++i){
      bf16x8 afrag = *(const bf16x8*)(Ap + (size_t)i*16*lda + k0);
      acc[i] = MFMA(afrag, bfrag, acc[i]);
    }
  }
  const float bv = bias ? bias[n_base + r] : 0.f;
  #pragma unroll
  for (int i = 0; i < 4; ++i)
    #pragma unroll
    for (int q = 0; q < 4; ++q)
      C[(size_t)(m_base + i*16 + half*4 + q)*ldc + n_base + r] =
          __float2bfloat16(acc[i][q] + bv);
}

// ---------------- the 32-step scan: direct L2->VGPR stream, depth-2, paced ----------
// 128 blocks x 512 threads. Weights never touch LDS: Wb0/Wb1 double-buffer in
// registers, vmcnt(4) pacing, all reload addresses compile-time static.
// gi packed bf16 in 24 regs (r13-verified numerics). 4 barriers/step. LDS 35KB.
__global__ __launch_bounds__(512, 1) void mega16_kernel(
    const bf16_t* __restrict__ gi16,       // [B][1536] bf16, incl biases
    const bf16_t* __restrict__ sA,
    const bf16_t* __restrict__ sB,
    const bf16_t* __restrict__ sC,
    const bf16_t* __restrict__ w_ssn,
    const float* __restrict__ lin1_b,
    const float* __restrict__ lin2_b,
    const float* __restrict__ b_hh,
    const float* __restrict__ gt,
    const int* __restrict__ line_prob,
    const float* __restrict__ sample_prob,
    float* __restrict__ out){
  __shared__ bf16_t lds_x[MB][LDX];      // [h(512) | ss(42) | zeros]
  __shared__ bf16_t o1s[MB][LDH];
  const int tid = threadIdx.x;
  const int wv = tid >> 6, l = tid & 63;
  const int lr = l & 15, half = l >> 4;
  const int m0 = blockIdx.x * MB;
  const int colbase = wv * 64;
  const int rowoff = (colbase + lr)*32 + (half ^ ((lr >> 1) & 3))*8;

  for (int i = tid; i < MB*LDX/2; i += 512) ((uint32_t*)lds_x)[i] = 0u;

  // ---- gi slice, packed bf16: gip[gate][ti][p] holds rows q=2p(lo),2p+1(hi) ----
  uint32_t gip[3][4][2];
  #pragma unroll
  for (int g = 0; g < 3; ++g)
    #pragma unroll
    for (int ti = 0; ti < 4; ++ti)
      #pragma unroll
      for (int p = 0; p < 2; ++p){
        const bf16_t* gp = gi16 + (size_t)(m0 + half*4 + 2*p)*G3
                          + g*512 + colbase + ti*16 + lr;
        uint32_t lo = *(const uint16_t*)gp;
        uint32_t hi = *(const uint16_t*)(gp + G3);
        gip[g][ti][p] = lo | (hi << 16);
      }
  float bhn[4], lb1[4];
  #pragma unroll
  for (int ti = 0; ti < 4; ++ti){
    bhn[ti] = b_hh[1024 + colbase + ti*16 + lr];
    lb1[ti] = lin1_b[colbase + ti*16 + lr];
  }
  const int j3 = wv*16 + lr;
  const float b2c = (wv < 3 && j3 < OUTSZ) ? lin2_b[j3] : 0.f;

  float hp[4][4] = {};

  const bf16_t* baseA = sA + rowoff;
  const bf16_t* baseB = sB + rowoff;
  const bf16_t* wsp   = w_ssn + (size_t)(colbase + lr)*64 + half*8;

  bf16x8 Wb0[4], Wb1[4];
  LOADW(Wb0, baseA);
  LOADW(Wb1, baseA + (size_t)CHW);
  __syncthreads();                       // lds_x zeros visible (drains prologue loads; one-time)

#define TICKA(G, WB, AV, RELSRC) do {   \
    WAITV4();                           \
    MFMA4(accA[G], AV, WB);             \
    LOADW(WB, RELSRC);                  \
  } while (0)

#define TICKB(I, WB, RELSRC) do {                                    \
    WAITV4();                                                        \
    union { u16x8 u; bf16x8 b; } va;                                 \
    va.u = *(const u16x8*)&lds_x[lr][(I)*32 + half*8];               \
    _Pragma("unroll")                                                \
    for (int e = 0; e < 8; ++e)                                      \
      if (va.u[e] & 0x8000) va.u[e] = 0;                             \
    MFMA4(accB, va.b, WB);                                           \
    LOADW(WB, RELSRC);                                               \
  } while (0)

  #pragma unroll 1
  for (int t = 0; t < NL; ++t){
    // ============ phase A: 54 ticks, reg double-buffer, no barriers ============
    f32x4 accA[3][4] = {};
    {
      const bf16_t* rl = baseA + 2*(size_t)CHW;
      #pragma unroll 1
      for (int k0 = 0; k0 < 16; k0 += 2){
        bf16x8 a0 = *(const bf16x8*)&lds_x[lr][k0*32 + half*8];
        bf16x8 a1 = *(const bf16x8*)&lds_x[lr][(k0+1)*32 + half*8];
        TICKA(0, Wb0, a0, rl); rl += CHW;
        TICKA(1, Wb1, a0, rl); rl += CHW;
        TICKA(2, Wb0, a0, rl); rl += CHW;
        TICKA(0, Wb1, a1, rl); rl += CHW;
        TICKA(1, Wb0, a1, rl); rl += CHW;
        TICKA(2, Wb1, a1, rl); rl += CHW;
      }
      // k0 = 16,17: reloads cross into sB (chunks 54,55)
      bf16x8 a0 = *(const bf16x8*)&lds_x[lr][16*32 + half*8];
      bf16x8 a1 = *(const bf16x8*)&lds_x[lr][17*32 + half*8];
      TICKA(0, Wb0, a0, baseA + 50*(size_t)CHW);
      TICKA(1, Wb1, a0, baseA + 51*(size_t)CHW);
      TICKA(2, Wb0, a0, baseA + 52*(size_t)CHW);
      TICKA(0, Wb1, a1, baseA + 53*(size_t)CHW);
      TICKA(1, Wb0, a1, baseB);
      TICKA(2, Wb1, a1, baseB + (size_t)CHW);
    }

    // ---- ssn (transient weight loads; reads lds_x ss cols) ----
    f32x4 accS[4] = {};
    #pragma unroll
    for (int ks = 0; ks < 2; ++ks){
      bf16x8 a2 = *(const bf16x8*)&lds_x[lr][512 + ks*32 + half*8];
      #pragma unroll
      for (int ti = 0; ti < 4; ++ti){
        bf16x8 ws = *(const bf16x8*)(wsp + (size_t)ti*16*64 + ks*32);
        accS[ti] = MFMA(a2, ws, accS[ti]);
      }
    }
    PHASE_SYNC();    // (1) all waves' lds_x reads done before gates rewrite h

    // ---- gates (gi unpacked from packed bf16 registers) ----
    #pragma unroll
    for (int ti = 0; ti < 4; ++ti)
      #pragma unroll
      for (int p = 0; p < 2; ++p)
        #pragma unroll
        for (int qq = 0; qq < 2; ++qq){
          const int q = 2*p + qq;
          float gr = qq ? bf_hi(gip[0][ti][p]) : bf_lo(gip[0][ti][p]);
          float gz = qq ? bf_hi(gip[1][ti][p]) : bf_lo(gip[1][ti][p]);
          float gn = qq ? bf_hi(gip[2][ti][p]) : bf_lo(gip[2][ti][p]);
          float ir = accA[0][ti][q] + gr;
          float iz = accA[1][ti][q] + gz;
          float hn = accA[2][ti][q] + bhn[ti];
          float gnn = gn + accS[ti][q];
          float r = sigmoidf_(ir);
          float z = sigmoidf_(iz);
          float n = tanhf(gnn + r*hn);
          float hv = (1.f - z)*n + z*hp[ti][q];
          hp[ti][q] = hv;
          lds_x[half*4 + q][colbase + ti*16 + lr] = __float2bfloat16(hv);
        }
    PHASE_SYNC();    // (2) h visible to all waves

    // ============ phase B: 16 ticks, fully static; tail preloads next-A 0,1 ============
    f32x4 accB[4] = {};
    TICKB(0,  Wb0, baseB + 2*(size_t)CHW);
    TICKB(1,  Wb1, baseB + 3*(size_t)CHW);
    TICKB(2,  Wb0, baseB + 4*(size_t)CHW);
    TICKB(3,  Wb1, baseB + 5*(size_t)CHW);
    TICKB(4,  Wb0, baseB + 6*(size_t)CHW);
    TICKB(5,  Wb1, baseB + 7*(size_t)CHW);
    TICKB(6,  Wb0, baseB + 8*(size_t)CHW);
    TICKB(7,  Wb1, baseB + 9*(size_t)CHW);
    TICKB(8,  Wb0, baseB + 10*(size_t)CHW);
    TICKB(9,  Wb1, baseB + 11*(size_t)CHW);
    TICKB(10, Wb0, baseB + 12*(size_t)CHW);
    TICKB(11, Wb1, baseB + 13*(size_t)CHW);
    TICKB(12, Wb0, baseB + 14*(size_t)CHW);
    TICKB(13, Wb1, baseB + 15*(size_t)CHW);
    TICKB(14, Wb0, baseA);                  // next step's chunk 0
    TICKB(15, Wb1, baseA + (size_t)CHW);    // next step's chunk 1
    #pragma unroll
    for (int ti = 0; ti < 4; ++ti)
      #pragma unroll
      for (int q = 0; q < 4; ++q)
        o1s[half*4 + q][colbase + ti*16 + lr] =
            __float2bfloat16(fmaxf(accB[ti][q] + lb1[ti], 0.f));
    PHASE_SYNC();    // (3) o1s visible (lin2 weights come from global — no ring hazard)

    // ============ phase C: lin2 direct from L2 (waves 0..2) + outputs + ss ============
    if (wv < 3){
      f32x4 accC = {};
      #pragma unroll
      for (int n = 0; n < 2; ++n)
        #pragma unroll
        for (int k0 = 0; k0 < 8; ++k0){
          bf16x8 a = *(const bf16x8*)&o1s[lr][(n*8 + k0)*32 + half*8];
          int sg = (k0*4 + half) ^ (j3 & 7);
          bf16x8 bf = *(const bf16x8*)(sC + (size_t)n*CHW + j3*256 + sg*8);
          accC = MFMA(a, bf, accC);
        }
      #pragma unroll
      for (int q = 0; q < 4; ++q){
        float val = accC[q] + b2c;
        int row = half*4 + q;
        int bm = m0 + row;
        if (j3 < 40){
          out[((size_t)bm*NL + t)*40 + j3] = val;
        } else if (j3 < 42){
          float other = __shfl_xor(val, 1);
          float mx = fmaxf(val, other);
          float e0 = __expf(val - mx), e1 = __expf(other - mx);
          out[(size_t)B*NL*40 + ((size_t)bm*NL + t)*2 + (j3 - 40)] = e0/(e0 + e1);
        }
        if (t + 1 < NL && j3 < OUTSZ){
          bool up = sample_prob[(size_t)(t+1)*B + bm] < 0.1f;
          float gtv;
          if (j3 < 40) gtv = gt[((size_t)bm*NL + t)*40 + j3];
          else {
            float pv = (float)line_prob[bm*NL + t];
            gtv = (j3 == 40) ? 1.f - pv : pv;
          }
          lds_x[row][512 + j3] = __float2bfloat16(up ? val : gtv);
        }
      }
    }
    PHASE_SYNC();    // (4) ss visible for next step's A/ssn reads
  }
}

extern "C" void kernel_launch(void* const* d_in, const int* in_sizes, int n_in,
                              void* d_out, int out_size, void* d_ws, size_t ws_size,
                              hipStream_t stream) {
  const float* img         = (const float*)d_in[0];
  const float* gt          = (const float*)d_in[1];
  const int*   line_prob   = (const int*)d_in[2];
  const float* sample_prob = (const float*)d_in[3];
  const float* att_w       = (const float*)d_in[4];
  // d_in[5] att_b: unused — softmax shift-invariance cancels it
  const float* w_ih        = (const float*)d_in[6];
  const float* w_hh        = (const float*)d_in[7];
  const float* b_ih        = (const float*)d_in[8];
  const float* b_hh        = (const float*)d_in[9];
  const float* lin1_w      = (const float*)d_in[10];
  const float* lin1_b      = (const float*)d_in[11];
  const float* lin2_w      = (const float*)d_in[12];
  const float* lin2_b      = (const float*)d_in[13];
  float* out = (float*)d_out;

  char* p = (char*)d_ws;
  auto alloc = [&](size_t bytes){ void* q = p; p += (bytes + 255) & ~(size_t)255; return q; };
  bf16_t* gi16      = (bf16_t*)alloc((size_t)B*G3*2);
  bf16_t* att_bf    = (bf16_t*)alloc((size_t)B*FEAT*2);
  bf16_t* sA        = (bf16_t*)alloc((size_t)54*CHW*2);
  bf16_t* sB        = (bf16_t*)alloc((size_t)16*CHW*2);
  bf16_t* sC        = (bf16_t*)alloc((size_t)2*CHW*2);
  bf16_t* w_ssn     = (bf16_t*)alloc((size_t)512*64*2);
  bf16_t* w_ih512b  = (bf16_t*)alloc((size_t)G3*512*2);
  float*  bias_comb = (float*)alloc((size_t)G3*4);

  prep4_kernel<<<4096, 256, 0, stream>>>(w_ih, w_hh, lin1_w, lin2_w, b_ih, b_hh,
                                         sA, sB, sC, w_ssn, w_ih512b, bias_comb);
  att_kernel<<<B, 256, 0, stream>>>(img, att_w, att_bf);
  gemm_mfma_bf<<<dim3(G3/64, B/64), 256, 0, stream>>>(att_bf, w_ih512b, bias_comb, gi16,
                                                      512, 512, 512, G3);
  mega16_kernel<<<NBLK, 512, 0, stream>>>(gi16, sA, sB, sC, w_ssn, lin1_b, lin2_b,
                                          b_hh, gt, line_prob, sample_prob, out);
}